// Round 2
// baseline (750.760 us; speedup 1.0000x reference)
//
#include <hip/hip_runtime.h>
#include <math.h>

#define DDIM 64
#define SCANB 1024              // nodes per scan block
#define MAXNB 128               // max scan blocks (NB = ceil(100000/1024) = 98)
#define FXBITS 40               // packed: fixed-point degree [0,40), count [40,64)
#define FXMASK 0xFFFFFFFFFFull

typedef unsigned long long ull;
typedef _Float16 half2_t __attribute__((ext_vector_type(2)));

__device__ inline unsigned int pk_f16x2(float lo, float hi) {
    return __builtin_bit_cast(unsigned int, __builtin_amdgcn_cvt_pkrtz(lo, hi));
}

__device__ inline half2_t dup_lo16(unsigned int s) {    // (s&0xFFFF) in both halves
    return __builtin_bit_cast(half2_t, __builtin_amdgcn_perm(0u, s, 0x01000100u));
}

__device__ inline half2_t h2_shfl_xor(half2_t v, int off) {
    return __builtin_bit_cast(half2_t, __shfl_xor(__builtin_bit_cast(unsigned int, v), off));
}

__device__ inline ull pack_edge(float v) {
    return (1ull << FXBITS) | (ull)(unsigned)(int)(v * 65536.0f + 0.5f);
}

// ---- zero packed histogram arrays ----
__global__ void zero_kernel(ull* __restrict__ p, long n) {
    long i = (long)blockIdx.x * blockDim.x + threadIdx.x;
    if (i < n) p[i] = 0;
}

// ---- hist: one packed ull atomic per edge per direction (count<<40 | deg*2^16) ----
__global__ __launch_bounds__(256)
void hist_kernel(const int* __restrict__ erow, const int* __restrict__ ecol,
                 const float* __restrict__ evals,
                 ull* __restrict__ pr, ull* __restrict__ pc, int E) {
    int nq = E >> 2;
    for (int p = blockIdx.x * 256 + threadIdx.x; p < nq; p += gridDim.x * 256) {
        int i = p << 2;
        int4 r4 = *(const int4*)(erow + i);
        int4 c4 = *(const int4*)(ecol + i);
        float4 v4 = *(const float4*)(evals + i);
        ull fx = pack_edge(v4.x);
        ull fy = pack_edge(v4.y);
        ull fz = pack_edge(v4.z);
        ull fw = pack_edge(v4.w);
        atomicAdd(&pr[r4.x], fx);
        atomicAdd(&pr[r4.y], fy);
        atomicAdd(&pr[r4.z], fz);
        atomicAdd(&pr[r4.w], fw);
        atomicAdd(&pc[c4.x], fx);
        atomicAdd(&pc[c4.y], fy);
        atomicAdd(&pc[c4.z], fz);
        atomicAdd(&pc[c4.w], fw);
    }
    if (blockIdx.x == 0 && threadIdx.x == 0) {
        for (int i = nq << 2; i < E; i++) {
            ull f = pack_edge(evals[i]);
            atomicAdd(&pr[erow[i]], f);
            atomicAdd(&pc[ecol[i]], f);
        }
    }
}

// ---- scan1: per-block scan of mod-4-rounded counts; inv_r/inv_c from packed ----
__global__ __launch_bounds__(SCANB)
void scan1_kernel(const ull* __restrict__ pr, const ull* __restrict__ pc,
                  int* __restrict__ excl, int* __restrict__ btot,
                  float* __restrict__ inv_r, float* __restrict__ inv_c) {
    __shared__ int tot[SCANB];
    int b = blockIdx.x, t = threadIdx.x;
    int node = b * SCANB + t;
    ull p = pr[node];
    ull q = pc[node];
    int cnt = (int)(p >> FXBITS);
    float deg  = (float)((double)(p & FXMASK) * (1.0 / 65536.0));
    float degc = (float)((double)(q & FXMASK) * (1.0 / 65536.0));
    inv_r[node] = 1.0f / (sqrtf(deg)  + 1e-8f);
    inv_c[node] = 1.0f / (sqrtf(degc) + 1e-8f);
    int sum4 = (cnt + 3) & ~3;           // mod-4 row slots -> 16B-aligned cw quads in spmm
    tot[t] = sum4;
    __syncthreads();
    for (int off = 1; off < SCANB; off <<= 1) {
        int v = (t >= off) ? tot[t - off] : 0;
        __syncthreads();
        tot[t] += v;
        __syncthreads();
    }
    excl[node] = tot[t] - sum4;
    if (t == SCANB - 1) btot[b] = tot[t];
}

// ---- finalize: inline scan of block totals -> rse + placement cursors ----
__global__ __launch_bounds__(SCANB)
void finalize_kernel(const ull* __restrict__ pr, const int* __restrict__ excl,
                     const int* __restrict__ btot,
                     int2* __restrict__ rse, int* __restrict__ cur, int N, int NB) {
    __shared__ int bo[MAXNB];
    int b = blockIdx.x, t = threadIdx.x;
    if (t < MAXNB) bo[t] = (t < NB) ? btot[t] : 0;
    __syncthreads();
    for (int off = 1; off < MAXNB; off <<= 1) {
        int v = 0;
        if (t >= off && t < MAXNB) v = bo[t - off];
        __syncthreads();
        if (t < MAXNB) bo[t] += v;
        __syncthreads();
    }
    int base = (b == 0) ? 0 : bo[b - 1];
    int node = b * SCANB + t;
    int cnt = (int)(pr[node] >> FXBITS);
    int st = base + excl[node];
    if (node < N) {
        int2 se;
        se.x = st;
        se.y = st + cnt;
        rse[node] = se;
    }
    cur[node] = st;
}

// ---- place2: second edge pass; ranked placement via global cursors ----
__global__ __launch_bounds__(256)
void place2_kernel(const int* __restrict__ erow, const int* __restrict__ ecol,
                   const float* __restrict__ evals,
                   const float* __restrict__ inv_r, const float* __restrict__ inv_c,
                   int* __restrict__ cur, unsigned int* __restrict__ cw, int E) {
    int nq = E >> 2;
    for (int p = blockIdx.x * 256 + threadIdx.x; p < nq; p += gridDim.x * 256) {
        int i = p << 2;
        int4 r4 = *(const int4*)(erow + i);
        int4 c4 = *(const int4*)(ecol + i);
        float4 v4 = *(const float4*)(evals + i);
        int pos0 = atomicAdd(&cur[r4.x], 1);
        int pos1 = atomicAdd(&cur[r4.y], 1);
        int pos2 = atomicAdd(&cur[r4.z], 1);
        int pos3 = atomicAdd(&cur[r4.w], 1);
        float w0 = v4.x * inv_r[r4.x] * inv_c[c4.x];
        float w1 = v4.y * inv_r[r4.y] * inv_c[c4.y];
        float w2 = v4.z * inv_r[r4.z] * inv_c[c4.z];
        float w3 = v4.w * inv_r[r4.w] * inv_c[c4.w];
        cw[pos0] = ((unsigned)c4.x << 15) | ((pk_f16x2(w0, w0) & 0xFFFFu) >> 1);
        cw[pos1] = ((unsigned)c4.y << 15) | ((pk_f16x2(w1, w1) & 0xFFFFu) >> 1);
        cw[pos2] = ((unsigned)c4.z << 15) | ((pk_f16x2(w2, w2) & 0xFFFFu) >> 1);
        cw[pos3] = ((unsigned)c4.w << 15) | ((pk_f16x2(w3, w3) & 0xFFFFu) >> 1);
    }
    if (blockIdx.x == 0 && threadIdx.x == 0) {
        for (int i = nq << 2; i < E; i++) {
            int r = erow[i], c = ecol[i];
            int pos = atomicAdd(&cur[r], 1);
            float w = evals[i] * inv_r[r] * inv_c[c];
            cw[pos] = ((unsigned)c << 15) | ((pk_f16x2(w, w) & 0xFFFFu) >> 1);
        }
    }
}

// ---- cvt: fb0 = f16(nf); 4 floats/thread (acc init folded into spmm layer 1) ----
__global__ void cvt_kernel(const float* __restrict__ src,
                           unsigned int* __restrict__ dst, long n4) {
    long i = (long)blockIdx.x * blockDim.x + threadIdx.x;
    if (i < n4) {
        float4 v = ((const float4*)src)[i];
        uint2 o;
        o.x = pk_f16x2(v.x, v.y);
        o.y = pk_f16x2(v.z, v.w);
        ((uint2*)dst)[i] = o;
    }
}

// ---- SpMM: wave per row, 32 edges/iter via uint4 cw quads, batched gathers ----
// (unchanged this round to isolate preprocessing rewrite)
__global__ __launch_bounds__(256)
void spmm_f16_kernel(const int2* __restrict__ rse,
                     const unsigned int* __restrict__ cw,
                     const unsigned short* __restrict__ fin,
                     unsigned short* __restrict__ fout,
                     unsigned short* __restrict__ acc16, int N,
                     int writeOut, int initAcc) {
    int wid = blockIdx.x * (blockDim.x >> 6) + (threadIdx.x >> 6);   // row
    if (wid >= N) return;
    int lane = threadIdx.x & 63;
    int g = lane >> 3;          // edge-quad slot 0..7 (32 edges per iteration)
    int h = lane & 7;           // feature chunk (8 f16 = 16 B)
    int2 se = rse[wid];
    int s = se.x, e = se.y;     // s multiple of 4 -> uint4-aligned cw quads
    uint4* ap = (uint4*)(acc16 + ((long)wid << 6)) + h;
    uint4 old = initAcc ? ((const uint4*)(fin + ((long)wid << 6)))[h] : *ap;
    half2_t a2[8];
    #pragma unroll
    for (int k = 0; k < 8; k++) a2[k] = (half2_t)0;

    for (int base = s; base < e; base += 32) {
        int j = base + 4 * g;
        if (j < e) {
            uint4 pw = *(const uint4*)(cw + j);
            int c0 = (int)(pw.x >> 15);
            int c1 = (j + 1 < e) ? (int)(pw.y >> 15) : c0;
            int c2 = (j + 2 < e) ? (int)(pw.z >> 15) : c0;
            int c3 = (j + 3 < e) ? (int)(pw.w >> 15) : c0;
            uint4 q0 = ((const uint4*)(fin + ((long)c0 << 6)))[h];
            uint4 q1 = ((const uint4*)(fin + ((long)c1 << 6)))[h];
            uint4 q2 = ((const uint4*)(fin + ((long)c2 << 6)))[h];
            uint4 q3 = ((const uint4*)(fin + ((long)c3 << 6)))[h];
            half2_t w0 = dup_lo16(pw.x << 1);
            half2_t w1 = (j + 1 < e) ? dup_lo16(pw.y << 1) : (half2_t)0;
            half2_t w2 = (j + 2 < e) ? dup_lo16(pw.z << 1) : (half2_t)0;
            half2_t w3 = (j + 3 < e) ? dup_lo16(pw.w << 1) : (half2_t)0;
            a2[0] += w0 * __builtin_bit_cast(half2_t, q0.x);
            a2[1] += w0 * __builtin_bit_cast(half2_t, q0.y);
            a2[2] += w0 * __builtin_bit_cast(half2_t, q0.z);
            a2[3] += w0 * __builtin_bit_cast(half2_t, q0.w);
            a2[4] += w1 * __builtin_bit_cast(half2_t, q1.x);
            a2[5] += w1 * __builtin_bit_cast(half2_t, q1.y);
            a2[6] += w1 * __builtin_bit_cast(half2_t, q1.z);
            a2[7] += w1 * __builtin_bit_cast(half2_t, q1.w);
            a2[0] += w2 * __builtin_bit_cast(half2_t, q2.x);
            a2[1] += w2 * __builtin_bit_cast(half2_t, q2.y);
            a2[2] += w2 * __builtin_bit_cast(half2_t, q2.z);
            a2[3] += w2 * __builtin_bit_cast(half2_t, q2.w);
            a2[4] += w3 * __builtin_bit_cast(half2_t, q3.x);
            a2[5] += w3 * __builtin_bit_cast(half2_t, q3.y);
            a2[6] += w3 * __builtin_bit_cast(half2_t, q3.z);
            a2[7] += w3 * __builtin_bit_cast(half2_t, q3.w);
        }
    }

    // packed-f16 epilogue
    #pragma unroll
    for (int k = 0; k < 4; k++) a2[k] += a2[k + 4];
    #pragma unroll
    for (int k = 0; k < 4; k++) {
        a2[k] += h2_shfl_xor(a2[k], 8);
        a2[k] += h2_shfl_xor(a2[k], 16);
        a2[k] += h2_shfl_xor(a2[k], 32);
    }
    half2_t ssh = a2[0] * a2[0];
    ssh += a2[1] * a2[1];
    ssh += a2[2] * a2[2];
    ssh += a2[3] * a2[3];
    float ss = (float)ssh[0] + (float)ssh[1];
    ss += __shfl_xor(ss, 1);
    ss += __shfl_xor(ss, 2);
    ss += __shfl_xor(ss, 4);
    float s2 = fminf(1.0f / fmaxf(sqrtf(ss), 1e-12f), 6.0e4f);  // clamp: f16-safe
    if (g == 0) {
        if (writeOut) {
            uint4 o;
            o.x = __builtin_bit_cast(unsigned int, a2[0]);
            o.y = __builtin_bit_cast(unsigned int, a2[1]);
            o.z = __builtin_bit_cast(unsigned int, a2[2]);
            o.w = __builtin_bit_cast(unsigned int, a2[3]);
            ((uint4*)(fout + ((long)wid << 6)))[h] = o;
        }
        half2_t s2h = __builtin_bit_cast(half2_t, pk_f16x2(s2, s2));
        uint4 nw;
        nw.x = __builtin_bit_cast(unsigned int, __builtin_bit_cast(half2_t, old.x) + a2[0] * s2h);
        nw.y = __builtin_bit_cast(unsigned int, __builtin_bit_cast(half2_t, old.y) + a2[1] * s2h);
        nw.z = __builtin_bit_cast(unsigned int, __builtin_bit_cast(half2_t, old.z) + a2[2] * s2h);
        nw.w = __builtin_bit_cast(unsigned int, __builtin_bit_cast(half2_t, old.w) + a2[3] * s2h);
        *ap = nw;
    }
}

// ---- BPR loss (acc in f16) ----
__global__ void loss_terms_kernel(const unsigned short* __restrict__ acc16,
                                  const int* __restrict__ a_id, const int* __restrict__ p_id,
                                  const int* __restrict__ n_id,
                                  float* __restrict__ terms, int B) {
    long gid = (long)blockIdx.x * blockDim.x + threadIdx.x;
    int b = (int)(gid >> 6);
    int lane = threadIdx.x & 63;
    if (b < B) {
        int ia = a_id[b], ip = p_id[b], in2 = n_id[b];
        float a = (float)__builtin_bit_cast(_Float16, acc16[(long)ia * DDIM + lane]);
        float p = (float)__builtin_bit_cast(_Float16, acc16[(long)ip * DDIM + lane]);
        float n = (float)__builtin_bit_cast(_Float16, acc16[(long)in2 * DDIM + lane]);
        float dp = a * p, dn = a * n;
        #pragma unroll
        for (int off = 1; off < 64; off <<= 1) { dp += __shfl_xor(dp, off); dn += __shfl_xor(dn, off); }
        if (lane == 0) {
            float x = (dp - dn) * 0.0625f;   // node_rep = acc/4 -> preds scale 1/16
            terms[b] = fmaxf(-x, 0.0f) + log1pf(expf(-fabsf(x)));
        }
    }
}

__global__ void reduce_kernel(const float* __restrict__ terms, float* __restrict__ out, int B) {
    __shared__ float sm[256];
    float s = 0.0f;
    for (int i = threadIdx.x; i < B; i += 256) s += terms[i];
    sm[threadIdx.x] = s;
    __syncthreads();
    for (int stride = 128; stride > 0; stride >>= 1) {
        if (threadIdx.x < stride) sm[threadIdx.x] += sm[threadIdx.x + stride];
        __syncthreads();
    }
    if (threadIdx.x == 0) out[0] = sm[0] / (float)B;
}

extern "C" void kernel_launch(void* const* d_in, const int* in_sizes, int n_in,
                              void* d_out, int out_size, void* d_ws, size_t ws_size,
                              hipStream_t stream) {
    const float* nf    = (const float*)d_in[0];
    const int*   erow  = (const int*)d_in[1];
    const int*   ecol  = (const int*)d_in[2];
    const float* evals = (const float*)d_in[3];
    const int*   a_id  = (const int*)d_in[4];
    const int*   p_id  = (const int*)d_in[5];
    const int*   n_id  = (const int*)d_in[6];

    int N = in_sizes[0] / DDIM;
    int E = in_sizes[1];
    int B = in_sizes[4];
    int NB = (N + SCANB - 1) / SCANB;
    int Npad = NB * SCANB;

    size_t featB16 = (size_t)N * DDIM * 2;
    size_t cwWords = (size_t)E + 3 * (size_t)N + 256;   // mod-4 row pad + quad overread pad

    char* w = (char*)d_ws;
    unsigned short* fb0 = (unsigned short*)w;  w += (featB16 + 255) & ~(size_t)255;
    unsigned short* fb1 = (unsigned short*)w;  w += (featB16 + 255) & ~(size_t)255;
    unsigned short* acc16 = (unsigned short*)w; w += (featB16 + 255) & ~(size_t)255;
    unsigned int* cw = (unsigned int*)w;       w += (cwWords * 4 + 255) & ~(size_t)255;
    ull* packed_r = (ull*)w;                   w += (size_t)Npad * 8;
    ull* packed_c = (ull*)w;                   w += (size_t)Npad * 8;   // contiguous after packed_r
    float* inv_r = (float*)w;                  w += (size_t)Npad * 4;
    float* inv_c = (float*)w;                  w += (size_t)Npad * 4;
    int* excl = (int*)w;                       w += (size_t)Npad * 4;
    int* cur = (int*)w;                        w += (size_t)Npad * 4;
    int* btot = (int*)w;                       w += (size_t)MAXNB * 4;
    int2* rse = (int2*)w;                      w += (size_t)N * 8;
    float* terms = (float*)w;                  w += (size_t)B * 4;

    long nzero = 2L * Npad;                    // packed_r + packed_c contiguous
    zero_kernel<<<(unsigned)((nzero + 255) / 256), 256, 0, stream>>>(packed_r, nzero);
    hist_kernel<<<1024, 256, 0, stream>>>(erow, ecol, evals, packed_r, packed_c, E);
    scan1_kernel<<<NB, SCANB, 0, stream>>>(packed_r, packed_c, excl, btot, inv_r, inv_c);
    finalize_kernel<<<NB, SCANB, 0, stream>>>(packed_r, excl, btot, rse, cur, N, NB);
    place2_kernel<<<1024, 256, 0, stream>>>(erow, ecol, evals, inv_r, inv_c, cur, cw, E);

    long n4 = (long)N * DDIM / 4;
    cvt_kernel<<<(unsigned)((n4 + 255) / 256), 256, 0, stream>>>(nf, (unsigned int*)fb0, n4);

    unsigned spmmGrid = (unsigned)((N + 3) / 4);   // 4 waves (rows) per 256-thread block
    spmm_f16_kernel<<<spmmGrid, 256, 0, stream>>>(rse, cw, fb0, fb1,
                                                  (unsigned short*)acc16, N, 1, 1);
    spmm_f16_kernel<<<spmmGrid, 256, 0, stream>>>(rse, cw, fb1, fb0,
                                                  (unsigned short*)acc16, N, 1, 0);
    spmm_f16_kernel<<<spmmGrid, 256, 0, stream>>>(rse, cw, fb0, fb1,
                                                  (unsigned short*)acc16, N, 0, 0);

    loss_terms_kernel<<<(unsigned)(((long)B * 64 + 255) / 256), 256, 0, stream>>>(
        (const unsigned short*)acc16, a_id, p_id, n_id, terms, B);
    reduce_kernel<<<1, 256, 0, stream>>>(terms, (float*)d_out, B);
}

// Round 3
// 382.547 us; speedup vs baseline: 1.9625x; 1.9625x over previous
//
#include <hip/hip_runtime.h>
#include <math.h>

#define DDIM 64
#define BUCKET 1024             // nodes per binning bucket
#define LRSHIFT 17              // br-packed: col [0,17), lrow [17,27), val [32,64)
#define CMASK 0x1FFFF
#define LRMASK 0x3FF
#define NBLK 512
#define TPB_BIN 1024
#define NWV 16                  // waves per binning block
#define TPB_CP 512
#define MAXNB 128               // max buckets (NB = ceil(100000/1024) = 98)

typedef unsigned long long ull;
typedef _Float16 half2_t __attribute__((ext_vector_type(2)));

__device__ inline unsigned int bf16_hi(float v) {       // RNE bf16 bits in high 16
    unsigned int a = __float_as_uint(v);
    return (a + 0x7fffu + ((a >> 16) & 1u)) & 0xffff0000u;
}

__device__ inline unsigned int pk_f16x2(float lo, float hi) {
    return __builtin_bit_cast(unsigned int, __builtin_amdgcn_cvt_pkrtz(lo, hi));
}

__device__ inline half2_t dup_lo16(unsigned int s) {    // (s&0xFFFF) in both halves
    return __builtin_bit_cast(half2_t, __builtin_amdgcn_perm(0u, s, 0x01000100u));
}

__device__ inline half2_t h2_shfl_xor(half2_t v, int off) {
    return __builtin_bit_cast(half2_t, __shfl_xor(__builtin_bit_cast(unsigned int, v), off));
}

// ---- init global fill counters (cacheline-padded: stride 16 ints) ----
__global__ void init_fill_kernel(int* __restrict__ gfill_r, int* __restrict__ gfill_c,
                                 int NB, int cap) {
    int k = blockIdx.x * blockDim.x + threadIdx.x;
    if (k < NB) {
        gfill_r[k * 16] = k * cap;
        gfill_c[k * 16] = k * cap;
    }
}

// ---- fused binning: per-wave count, block reserve, REGISTER-CACHED place ----
__global__ __launch_bounds__(TPB_BIN)
void binning_kernel(const int* __restrict__ erow, const int* __restrict__ ecol,
                    const float* __restrict__ evals,
                    int* __restrict__ gfill_r, int* __restrict__ gfill_c,
                    ull* __restrict__ br, unsigned int* __restrict__ bc,
                    int E, int NB, int chunk) {
    __shared__ int hr[NWV][MAXNB];
    __shared__ int hc[NWV][MAXNB];
    __shared__ int fr[MAXNB];     // block-level fill cursors (row key)
    __shared__ int fc[MAXNB];     // block-level fill cursors (col key)
    int t = threadIdx.x;
    int wv = t >> 6;
    for (int k = t; k < NWV * MAXNB; k += TPB_BIN) { (&hr[0][0])[k] = 0; (&hc[0][0])[k] = 0; }
    __syncthreads();
    int lo = blockIdx.x * chunk;             // chunk multiple of 4 -> lo 16B-aligned
    int hi = min(E, lo + chunk);
    int nq = (hi - lo) >> 2;
    int rem = (hi - lo) & 3;
    // phase 1: per-wave count; cache edge data in registers (chunk <= 8*TPB -> <=2 iters)
    int p0 = t, p1 = t + TPB_BIN;
    bool h0 = p0 < nq, h1 = p1 < nq;
    int4 r40, c40, r41, c41;
    float4 v40, v41;
    if (h0) {
        int i = lo + 4 * p0;
        r40 = *(const int4*)(erow + i);
        c40 = *(const int4*)(ecol + i);
        v40 = *(const float4*)(evals + i);
        atomicAdd(&hr[wv][r40.x >> 10], 1);
        atomicAdd(&hr[wv][r40.y >> 10], 1);
        atomicAdd(&hr[wv][r40.z >> 10], 1);
        atomicAdd(&hr[wv][r40.w >> 10], 1);
        atomicAdd(&hc[wv][c40.x >> 10], 1);
        atomicAdd(&hc[wv][c40.y >> 10], 1);
        atomicAdd(&hc[wv][c40.z >> 10], 1);
        atomicAdd(&hc[wv][c40.w >> 10], 1);
    }
    if (h1) {
        int i = lo + 4 * p1;
        r41 = *(const int4*)(erow + i);
        c41 = *(const int4*)(ecol + i);
        v41 = *(const float4*)(evals + i);
        atomicAdd(&hr[wv][r41.x >> 10], 1);
        atomicAdd(&hr[wv][r41.y >> 10], 1);
        atomicAdd(&hr[wv][r41.z >> 10], 1);
        atomicAdd(&hr[wv][r41.w >> 10], 1);
        atomicAdd(&hc[wv][c41.x >> 10], 1);
        atomicAdd(&hc[wv][c41.y >> 10], 1);
        atomicAdd(&hc[wv][c41.z >> 10], 1);
        atomicAdd(&hc[wv][c41.w >> 10], 1);
    }
    if (t == 0) {
        for (int i = hi - rem; i < hi; i++) {
            atomicAdd(&hr[0][erow[i] >> 10], 1);
            atomicAdd(&hc[0][ecol[i] >> 10], 1);
        }
    }
    __syncthreads();
    // phase 2: ONE reservation per (block,bucket) -> long contiguous output runs
    if (t < NB) {
        int sr = 0, sc = 0;
        #pragma unroll
        for (int w2 = 0; w2 < NWV; w2++) { sr += hr[w2][t]; sc += hc[w2][t]; }
        fr[t] = atomicAdd(&gfill_r[t * 16], sr);
        fc[t] = atomicAdd(&gfill_c[t * 16], sc);
    }
    __syncthreads();
    // phase 3: place from registers (no global re-read)
    if (h0) {
        int pos0 = atomicAdd(&fr[r40.x >> 10], 1);
        int pos1 = atomicAdd(&fr[r40.y >> 10], 1);
        int pos2 = atomicAdd(&fr[r40.z >> 10], 1);
        int pos3 = atomicAdd(&fr[r40.w >> 10], 1);
        br[pos0] = ((ull)__float_as_uint(v40.x) << 32) | ((ull)(r40.x & 1023) << LRSHIFT) | (unsigned)c40.x;
        br[pos1] = ((ull)__float_as_uint(v40.y) << 32) | ((ull)(r40.y & 1023) << LRSHIFT) | (unsigned)c40.y;
        br[pos2] = ((ull)__float_as_uint(v40.z) << 32) | ((ull)(r40.z & 1023) << LRSHIFT) | (unsigned)c40.z;
        br[pos3] = ((ull)__float_as_uint(v40.w) << 32) | ((ull)(r40.w & 1023) << LRSHIFT) | (unsigned)c40.w;
        int q0 = atomicAdd(&fc[c40.x >> 10], 1);
        int q1 = atomicAdd(&fc[c40.y >> 10], 1);
        int q2 = atomicAdd(&fc[c40.z >> 10], 1);
        int q3 = atomicAdd(&fc[c40.w >> 10], 1);
        bc[q0] = bf16_hi(v40.x) | (unsigned)(c40.x & 1023);
        bc[q1] = bf16_hi(v40.y) | (unsigned)(c40.y & 1023);
        bc[q2] = bf16_hi(v40.z) | (unsigned)(c40.z & 1023);
        bc[q3] = bf16_hi(v40.w) | (unsigned)(c40.w & 1023);
    }
    if (h1) {
        int pos0 = atomicAdd(&fr[r41.x >> 10], 1);
        int pos1 = atomicAdd(&fr[r41.y >> 10], 1);
        int pos2 = atomicAdd(&fr[r41.z >> 10], 1);
        int pos3 = atomicAdd(&fr[r41.w >> 10], 1);
        br[pos0] = ((ull)__float_as_uint(v41.x) << 32) | ((ull)(r41.x & 1023) << LRSHIFT) | (unsigned)c41.x;
        br[pos1] = ((ull)__float_as_uint(v41.y) << 32) | ((ull)(r41.y & 1023) << LRSHIFT) | (unsigned)c41.y;
        br[pos2] = ((ull)__float_as_uint(v41.z) << 32) | ((ull)(r41.z & 1023) << LRSHIFT) | (unsigned)c41.z;
        br[pos3] = ((ull)__float_as_uint(v41.w) << 32) | ((ull)(r41.w & 1023) << LRSHIFT) | (unsigned)c41.w;
        int q0 = atomicAdd(&fc[c41.x >> 10], 1);
        int q1 = atomicAdd(&fc[c41.y >> 10], 1);
        int q2 = atomicAdd(&fc[c41.z >> 10], 1);
        int q3 = atomicAdd(&fc[c41.w >> 10], 1);
        bc[q0] = bf16_hi(v41.x) | (unsigned)(c41.x & 1023);
        bc[q1] = bf16_hi(v41.y) | (unsigned)(c41.y & 1023);
        bc[q2] = bf16_hi(v41.z) | (unsigned)(c41.z & 1023);
        bc[q3] = bf16_hi(v41.w) | (unsigned)(c41.w & 1023);
    }
    if (t == 0) {
        for (int i = hi - rem; i < hi; i++) {
            int r = erow[i], c = ecol[i];
            float v = evals[i];
            int pos = atomicAdd(&fr[r >> 10], 1);
            br[pos] = ((ull)__float_as_uint(v) << 32) | ((ull)(r & 1023) << LRSHIFT) | (unsigned)c;
            int pos2 = atomicAdd(&fc[c >> 10], 1);
            bc[pos2] = bf16_hi(v) | (unsigned)(c & 1023);
        }
    }
}

// ---- count: block (bucket b, chunk ch) reads its 1/8 edge slice ONCE, 4-edge ILP ----
__global__ __launch_bounds__(TPB_CP)
void count_kernel(const ull* __restrict__ br, const unsigned int* __restrict__ bc,
                  const int* __restrict__ gfill_r, const int* __restrict__ gfill_c,
                  int* __restrict__ subcnt, float* __restrict__ subds,
                  float* __restrict__ subdsc, int cap) {
    __shared__ int cnt[BUCKET];
    __shared__ float ds[BUCKET];
    __shared__ float dsc[BUCKET];
    int b = blockIdx.x >> 3, ch = blockIdx.x & 7;
    int t = threadIdx.x;
    for (int k = t; k < BUCKET; k += TPB_CP) { cnt[k] = 0; ds[k] = 0.0f; dsc[k] = 0.0f; }
    __syncthreads();
    int s = b * cap;                              // cap mult of 64
    int e = gfill_r[b * 16];
    int len = ((((e - s) + 7) >> 3) + 3) & ~3;    // slice length mult of 4
    int cs = s + ch * len, ce = min(e, cs + len);
    int m = cs + ((ce - cs) & ~3);
    for (int i = cs + 4 * t; i < m; i += 4 * TPB_CP) {
        ull p0 = br[i];
        ull p1 = br[i + 1];
        ull p2 = br[i + 2];
        ull p3 = br[i + 3];
        int lr0 = (int)((p0 >> LRSHIFT) & LRMASK);
        int lr1 = (int)((p1 >> LRSHIFT) & LRMASK);
        int lr2 = (int)((p2 >> LRSHIFT) & LRMASK);
        int lr3 = (int)((p3 >> LRSHIFT) & LRMASK);
        atomicAdd(&cnt[lr0], 1);
        atomicAdd(&cnt[lr1], 1);
        atomicAdd(&cnt[lr2], 1);
        atomicAdd(&cnt[lr3], 1);
        atomicAdd(&ds[lr0], __uint_as_float((unsigned)(p0 >> 32)));
        atomicAdd(&ds[lr1], __uint_as_float((unsigned)(p1 >> 32)));
        atomicAdd(&ds[lr2], __uint_as_float((unsigned)(p2 >> 32)));
        atomicAdd(&ds[lr3], __uint_as_float((unsigned)(p3 >> 32)));
    }
    if (t == 0) {
        for (int i = m; i < ce; i++) {
            ull p = br[i];
            int lr = (int)((p >> LRSHIFT) & LRMASK);
            atomicAdd(&cnt[lr], 1);
            atomicAdd(&ds[lr], __uint_as_float((unsigned)(p >> 32)));
        }
    }
    int e2 = gfill_c[b * 16];
    int len2 = ((((e2 - s) + 7) >> 3) + 3) & ~3;
    int cs2 = s + ch * len2, ce2 = min(e2, cs2 + len2);
    int m2 = cs2 + ((ce2 - cs2) & ~3);
    for (int i = cs2 + 4 * t; i < m2; i += 4 * TPB_CP) {
        uint4 p = *(const uint4*)(bc + i);
        atomicAdd(&dsc[p.x & 0x3FFu], __uint_as_float(p.x & 0xffff0000u));
        atomicAdd(&dsc[p.y & 0x3FFu], __uint_as_float(p.y & 0xffff0000u));
        atomicAdd(&dsc[p.z & 0x3FFu], __uint_as_float(p.z & 0xffff0000u));
        atomicAdd(&dsc[p.w & 0x3FFu], __uint_as_float(p.w & 0xffff0000u));
    }
    if (t == 0) {
        for (int i = m2; i < ce2; i++) {
            unsigned int p = bc[i];
            atomicAdd(&dsc[p & 0x3FFu], __uint_as_float(p & 0xffff0000u));
        }
    }
    __syncthreads();
    size_t base = ((size_t)b * 8 + ch) * BUCKET;
    for (int k = t; k < BUCKET; k += TPB_CP) {
        subcnt[base + k] = cnt[k];
        subds[base + k]  = ds[k];
        subdsc[base + k] = dsc[k];
    }
}

// ---- combine: quad-rounded scan -> rse (int2), per-chunk bases, inv_r, inv_c ----
__global__ __launch_bounds__(1024)
void combine_kernel(int* __restrict__ subcnt, const float* __restrict__ subds,
                    const float* __restrict__ subdsc,
                    int2* __restrict__ rse,
                    float* __restrict__ inv_r, float* __restrict__ inv_c,
                    int N, int cap) {
    __shared__ int tot[BUCKET];
    int b = blockIdx.x, t = threadIdx.x;
    size_t base = (size_t)b * 8 * BUCKET;
    int c8[8];
    int sum = 0;
    #pragma unroll
    for (int c = 0; c < 8; c++) { c8[c] = subcnt[base + c * BUCKET + t]; sum += c8[c]; }
    int sum2 = (sum + 3) & ~3;           // mod-4 slot count -> row starts 16B-aligned (uint4 cw)
    tot[t] = sum2;
    __syncthreads();
    for (int off = 1; off < BUCKET; off <<= 1) {
        int v = (t >= off) ? tot[t - off] : 0;
        __syncthreads();
        tot[t] += v;
        __syncthreads();
    }
    int excl = tot[t] - sum2;
    int node = b * BUCKET + t;
    int s = b * cap;
    if (node < N) {
        int2 se;
        se.x = s + excl;
        se.y = s + excl + sum;
        rse[node] = se;
    }
    int run = s + excl;
    #pragma unroll
    for (int c = 0; c < 8; c++) { int v = c8[c]; subcnt[base + c * BUCKET + t] = run; run += v; }
    float d = 0.0f, dc = 0.0f;
    #pragma unroll
    for (int c = 0; c < 8; c++) { d += subds[base + c * BUCKET + t]; dc += subdsc[base + c * BUCKET + t]; }
    inv_r[b * BUCKET + t] = 1.0f / (sqrtf(d) + 1e-8f);
    inv_c[b * BUCKET + t] = 1.0f / (sqrtf(dc) + 1e-8f);
}

// ---- place: ranked placement, 4-edge ILP; 4 B entry = col<<15 | f16w>>1 ----
__global__ __launch_bounds__(TPB_CP)
void place_kernel(const ull* __restrict__ br, const int* __restrict__ gfill_r,
                  const int* __restrict__ pbase, const float* __restrict__ inv_r,
                  const float* __restrict__ inv_c,
                  unsigned int* __restrict__ cw, int cap) {
    __shared__ int fill[BUCKET];
    __shared__ float irs[BUCKET];
    int b = blockIdx.x >> 3, ch = blockIdx.x & 7;
    int t = threadIdx.x;
    size_t pb = ((size_t)b * 8 + ch) * BUCKET;
    for (int k = t; k < BUCKET; k += TPB_CP) {
        fill[k] = pbase[pb + k];
        irs[k]  = inv_r[b * BUCKET + k];
    }
    __syncthreads();
    int s = b * cap;
    int e = gfill_r[b * 16];
    int len = ((((e - s) + 7) >> 3) + 3) & ~3;
    int cs = s + ch * len, ce = min(e, cs + len);
    int m = cs + ((ce - cs) & ~3);
    for (int i = cs + 4 * t; i < m; i += 4 * TPB_CP) {
        ull p0 = br[i];
        ull p1 = br[i + 1];
        ull p2 = br[i + 2];
        ull p3 = br[i + 3];
        int c0 = (int)(p0 & CMASK), c1 = (int)(p1 & CMASK);
        int c2 = (int)(p2 & CMASK), c3 = (int)(p3 & CMASK);
        int lr0 = (int)((p0 >> LRSHIFT) & LRMASK);
        int lr1 = (int)((p1 >> LRSHIFT) & LRMASK);
        int lr2 = (int)((p2 >> LRSHIFT) & LRMASK);
        int lr3 = (int)((p3 >> LRSHIFT) & LRMASK);
        float v0 = __uint_as_float((unsigned)(p0 >> 32));
        float v1 = __uint_as_float((unsigned)(p1 >> 32));
        float v2 = __uint_as_float((unsigned)(p2 >> 32));
        float v3 = __uint_as_float((unsigned)(p3 >> 32));
        int pos0 = atomicAdd(&fill[lr0], 1);
        int pos1 = atomicAdd(&fill[lr1], 1);
        int pos2 = atomicAdd(&fill[lr2], 1);
        int pos3 = atomicAdd(&fill[lr3], 1);
        float w0 = v0 * inv_c[c0] * irs[lr0];
        float w1 = v1 * inv_c[c1] * irs[lr1];
        float w2 = v2 * inv_c[c2] * irs[lr2];
        float w3 = v3 * inv_c[c3] * irs[lr3];
        cw[pos0] = ((unsigned)c0 << 15) | ((pk_f16x2(w0, w0) & 0xFFFFu) >> 1);
        cw[pos1] = ((unsigned)c1 << 15) | ((pk_f16x2(w1, w1) & 0xFFFFu) >> 1);
        cw[pos2] = ((unsigned)c2 << 15) | ((pk_f16x2(w2, w2) & 0xFFFFu) >> 1);
        cw[pos3] = ((unsigned)c3 << 15) | ((pk_f16x2(w3, w3) & 0xFFFFu) >> 1);
    }
    if (t == 0) {
        for (int i = m; i < ce; i++) {
            ull p = br[i];
            int c = (int)(p & CMASK);
            int lr = (int)((p >> LRSHIFT) & LRMASK);
            float v = __uint_as_float((unsigned)(p >> 32));
            int pos = atomicAdd(&fill[lr], 1);
            float wv = v * inv_c[c] * irs[lr];
            cw[pos] = ((unsigned)c << 15) | ((pk_f16x2(wv, wv) & 0xFFFFu) >> 1);
        }
    }
}

// ---- cvt: fb0 = f16(nf); 4 floats/thread ----
__global__ void cvt_kernel(const float* __restrict__ src,
                           unsigned int* __restrict__ dst, long n4) {
    long i = (long)blockIdx.x * blockDim.x + threadIdx.x;
    if (i < n4) {
        float4 v = ((const float4*)src)[i];
        uint2 o;
        o.x = pk_f16x2(v.x, v.y);
        o.y = pk_f16x2(v.z, v.w);
        ((uint2*)dst)[i] = o;
    }
}

// ---- SpMM: wave per row, 32 edges/iter via uint4 cw quads, batched gathers ----
// acc/normalize epilogue REMOVED: layer outputs are raw segment sums; the loss
// kernel reconstructs rep = nf + sum_l x_l/||x_l|| for just the sampled rows.
__global__ __launch_bounds__(256)
void spmm_f16_kernel(const int2* __restrict__ rse,
                     const unsigned int* __restrict__ cw,
                     const unsigned short* __restrict__ fin,
                     unsigned short* __restrict__ fout, int N) {
    int wid = blockIdx.x * (blockDim.x >> 6) + (threadIdx.x >> 6);   // row
    if (wid >= N) return;
    int lane = threadIdx.x & 63;
    int g = lane >> 3;          // edge-quad slot 0..7 (32 edges per iteration)
    int h = lane & 7;           // feature chunk (8 f16 = 16 B)
    int2 se = rse[wid];
    int s = se.x, e = se.y;     // s multiple of 4 -> uint4-aligned cw quads
    half2_t a2[8];
    #pragma unroll
    for (int k = 0; k < 8; k++) a2[k] = (half2_t)0;

    for (int base = s; base < e; base += 32) {
        int j = base + 4 * g;
        if (j < e) {
            uint4 pw = *(const uint4*)(cw + j);
            int c0 = (int)(pw.x >> 15);
            int c1 = (j + 1 < e) ? (int)(pw.y >> 15) : c0;
            int c2 = (j + 2 < e) ? (int)(pw.z >> 15) : c0;
            int c3 = (j + 3 < e) ? (int)(pw.w >> 15) : c0;
            uint4 q0 = ((const uint4*)(fin + ((long)c0 << 6)))[h];
            uint4 q1 = ((const uint4*)(fin + ((long)c1 << 6)))[h];
            uint4 q2 = ((const uint4*)(fin + ((long)c2 << 6)))[h];
            uint4 q3 = ((const uint4*)(fin + ((long)c3 << 6)))[h];
            half2_t w0 = dup_lo16(pw.x << 1);
            half2_t w1 = (j + 1 < e) ? dup_lo16(pw.y << 1) : (half2_t)0;
            half2_t w2 = (j + 2 < e) ? dup_lo16(pw.z << 1) : (half2_t)0;
            half2_t w3 = (j + 3 < e) ? dup_lo16(pw.w << 1) : (half2_t)0;
            a2[0] += w0 * __builtin_bit_cast(half2_t, q0.x);
            a2[1] += w0 * __builtin_bit_cast(half2_t, q0.y);
            a2[2] += w0 * __builtin_bit_cast(half2_t, q0.z);
            a2[3] += w0 * __builtin_bit_cast(half2_t, q0.w);
            a2[4] += w1 * __builtin_bit_cast(half2_t, q1.x);
            a2[5] += w1 * __builtin_bit_cast(half2_t, q1.y);
            a2[6] += w1 * __builtin_bit_cast(half2_t, q1.z);
            a2[7] += w1 * __builtin_bit_cast(half2_t, q1.w);
            a2[0] += w2 * __builtin_bit_cast(half2_t, q2.x);
            a2[1] += w2 * __builtin_bit_cast(half2_t, q2.y);
            a2[2] += w2 * __builtin_bit_cast(half2_t, q2.z);
            a2[3] += w2 * __builtin_bit_cast(half2_t, q2.w);
            a2[4] += w3 * __builtin_bit_cast(half2_t, q3.x);
            a2[5] += w3 * __builtin_bit_cast(half2_t, q3.y);
            a2[6] += w3 * __builtin_bit_cast(half2_t, q3.z);
            a2[7] += w3 * __builtin_bit_cast(half2_t, q3.w);
        }
    }

    // reduce slot partials across lane groups; lanes g==0 hold/write the row
    #pragma unroll
    for (int k = 0; k < 4; k++) a2[k] += a2[k + 4];
    #pragma unroll
    for (int k = 0; k < 4; k++) {
        a2[k] += h2_shfl_xor(a2[k], 8);
        a2[k] += h2_shfl_xor(a2[k], 16);
        a2[k] += h2_shfl_xor(a2[k], 32);
    }
    if (g == 0) {
        uint4 o;
        o.x = __builtin_bit_cast(unsigned int, a2[0]);
        o.y = __builtin_bit_cast(unsigned int, a2[1]);
        o.z = __builtin_bit_cast(unsigned int, a2[2]);
        o.w = __builtin_bit_cast(unsigned int, a2[3]);
        ((uint4*)(fout + ((long)wid << 6)))[h] = o;
    }
}

// ---- loss: reconstruct rep rows on the fly (f32 norms, layer-0 from f32 nf) ----
__device__ inline float rep_at(const float* __restrict__ nf,
                               const unsigned short* __restrict__ f1,
                               const unsigned short* __restrict__ f2,
                               const unsigned short* __restrict__ f3,
                               int id, int lane) {
    long off = (long)id * DDIM + lane;
    float r  = nf[off];
    float v1 = (float)__builtin_bit_cast(_Float16, f1[off]);
    float v2 = (float)__builtin_bit_cast(_Float16, f2[off]);
    float v3 = (float)__builtin_bit_cast(_Float16, f3[off]);
    float s1 = v1 * v1, s2 = v2 * v2, s3 = v3 * v3;
    #pragma unroll
    for (int o = 1; o < 64; o <<= 1) {
        s1 += __shfl_xor(s1, o);
        s2 += __shfl_xor(s2, o);
        s3 += __shfl_xor(s3, o);
    }
    r += v1 / fmaxf(sqrtf(s1), 1e-12f);
    r += v2 / fmaxf(sqrtf(s2), 1e-12f);
    r += v3 / fmaxf(sqrtf(s3), 1e-12f);
    return r;
}

__global__ void loss_terms_kernel(const float* __restrict__ nf,
                                  const unsigned short* __restrict__ f1,
                                  const unsigned short* __restrict__ f2,
                                  const unsigned short* __restrict__ f3,
                                  const int* __restrict__ a_id, const int* __restrict__ p_id,
                                  const int* __restrict__ n_id,
                                  float* __restrict__ terms, int B) {
    long gid = (long)blockIdx.x * blockDim.x + threadIdx.x;
    int b = (int)(gid >> 6);
    int lane = threadIdx.x & 63;
    if (b < B) {
        float ra = rep_at(nf, f1, f2, f3, a_id[b], lane);
        float rp = rep_at(nf, f1, f2, f3, p_id[b], lane);
        float rn = rep_at(nf, f1, f2, f3, n_id[b], lane);
        float dp = ra * rp, dn = ra * rn;
        #pragma unroll
        for (int off = 1; off < 64; off <<= 1) { dp += __shfl_xor(dp, off); dn += __shfl_xor(dn, off); }
        if (lane == 0) {
            float x = (dp - dn) * 0.0625f;   // node_rep = rep/4 -> preds scale 1/16
            terms[b] = fmaxf(-x, 0.0f) + log1pf(expf(-fabsf(x)));
        }
    }
}

__global__ void reduce_kernel(const float* __restrict__ terms, float* __restrict__ out, int B) {
    __shared__ float sm[256];
    float s = 0.0f;
    for (int i = threadIdx.x; i < B; i += 256) s += terms[i];
    sm[threadIdx.x] = s;
    __syncthreads();
    for (int stride = 128; stride > 0; stride >>= 1) {
        if (threadIdx.x < stride) sm[threadIdx.x] += sm[threadIdx.x + stride];
        __syncthreads();
    }
    if (threadIdx.x == 0) out[0] = sm[0] / (float)B;
}

extern "C" void kernel_launch(void* const* d_in, const int* in_sizes, int n_in,
                              void* d_out, int out_size, void* d_ws, size_t ws_size,
                              hipStream_t stream) {
    const float* nf    = (const float*)d_in[0];
    const int*   erow  = (const int*)d_in[1];
    const int*   ecol  = (const int*)d_in[2];
    const float* evals = (const float*)d_in[3];
    const int*   a_id  = (const int*)d_in[4];
    const int*   p_id  = (const int*)d_in[5];
    const int*   n_id  = (const int*)d_in[6];

    int N = in_sizes[0] / DDIM;
    int E = in_sizes[1];
    int B = in_sizes[4];
    int NB = (N + BUCKET - 1) / BUCKET;
    int chunk = (((E + NBLK - 1) / NBLK) + 3) & ~3;   // multiple of 4 -> aligned quad loads
    int Npad = NB * BUCKET;

    // bucket capacity: mean + ~8.3% (15 sigma) + 5120 (mod-4 rounding pad 3072 + guard)
    long capl = ((long)E * BUCKET) / N;
    int cap = (int)(capl + capl / 12 + 5120);
    cap = (cap + 63) & ~63;

    size_t regionA = (size_t)cap * NB * 8;            // br (8 B), later fb0+fb1
    size_t regionB = (size_t)cap * NB * 4;            // bc (4 B), later cw (4 B)
    size_t featB16 = (size_t)N * DDIM * 2;
    if (regionA < 2 * featB16) regionA = 2 * featB16;
    size_t subBytes = (size_t)NB * 8 * BUCKET * 4;

    char* w = (char*)d_ws;
    ull*  br     = (ull*)w;
    char* regAp  = w;                 w += regionA;
    unsigned int* bc = (unsigned int*)w;
    unsigned int* cw = (unsigned int*)w;  w += regionB + 256;  // +256: spmm quad tail overread pad
    unsigned short* fb2 = (unsigned short*)w;  w += featB16;   // layer-2 output
    int* subcnt  = (int*)w;           w += subBytes;    // becomes pbase in combine
    float* subds = (float*)w;         w += subBytes;
    float* subdsc= (float*)w;         w += subBytes;
    float* inv_c = (float*)w;         w += (size_t)Npad * 4;
    float* inv_r = (float*)w;         w += (size_t)Npad * 4;
    int2* rse    = (int2*)w;          w += (size_t)N * 8;
    int* gfill_r = (int*)w;           w += (size_t)NB * 16 * 4;
    int* gfill_c = (int*)w;           w += (size_t)NB * 16 * 4;
    float* terms = (float*)w;         w += (size_t)B * 4;

    unsigned short* fb0 = (unsigned short*)regAp;             // aliases br (dead after place)
    unsigned short* fb1 = (unsigned short*)(regAp + featB16);

    init_fill_kernel<<<1, 128, 0, stream>>>(gfill_r, gfill_c, NB, cap);
    binning_kernel<<<NBLK, TPB_BIN, 0, stream>>>(erow, ecol, evals, gfill_r, gfill_c,
                                                 br, bc, E, NB, chunk);
    count_kernel<<<NB * 8, TPB_CP, 0, stream>>>(br, bc, gfill_r, gfill_c,
                                                subcnt, subds, subdsc, cap);
    combine_kernel<<<NB, 1024, 0, stream>>>(subcnt, subds, subdsc, rse,
                                            inv_r, inv_c, N, cap);
    place_kernel<<<NB * 8, TPB_CP, 0, stream>>>(br, gfill_r, subcnt, inv_r, inv_c, cw, cap);

    long n4 = (long)N * DDIM / 4;
    cvt_kernel<<<(unsigned)((n4 + 255) / 256), 256, 0, stream>>>(nf, (unsigned int*)fb0, n4);

    unsigned spmmGrid = (unsigned)((N + 3) / 4);   // 4 waves (rows) per 256-thread block
    // layers: fb0 -> fb1 -> fb2 -> fb0 (fb0 slot reused; loss reads f32 nf for layer 0)
    spmm_f16_kernel<<<spmmGrid, 256, 0, stream>>>(rse, cw, fb0, fb1, N);
    spmm_f16_kernel<<<spmmGrid, 256, 0, stream>>>(rse, cw, fb1, fb2, N);
    spmm_f16_kernel<<<spmmGrid, 256, 0, stream>>>(rse, cw, fb2, fb0, N);

    loss_terms_kernel<<<(unsigned)(((long)B * 64 + 255) / 256), 256, 0, stream>>>(
        nf, fb1, fb2, fb0, a_id, p_id, n_id, terms, B);
    reduce_kernel<<<1, 256, 0, stream>>>(terms, (float*)d_out, B);
}

// Round 4
// 367.519 us; speedup vs baseline: 2.0428x; 1.0409x over previous
//
#include <hip/hip_runtime.h>
#include <math.h>

#define DDIM 64
#define BUCKET 256              // nodes per bucket (fused count/scan/place is bucket-local)
#define LRSHIFT 17              // br-packed: col [0,17), lrow [17,25), val [32,64)
#define CMASK 0x1FFFF
#define LRMASK 0xFF
#define NBLK 512
#define TPB_BIN 1024
#define NWV 16                  // waves per binning block
#define MAXNB 400               // max buckets (NB = ceil(100000/256) = 391)

typedef unsigned long long ull;
typedef _Float16 half2_t __attribute__((ext_vector_type(2)));

__device__ inline unsigned int bf16_hi(float v) {       // RNE bf16 bits in high 16
    unsigned int a = __float_as_uint(v);
    return (a + 0x7fffu + ((a >> 16) & 1u)) & 0xffff0000u;
}

__device__ inline unsigned int pk_f16x2(float lo, float hi) {
    return __builtin_bit_cast(unsigned int, __builtin_amdgcn_cvt_pkrtz(lo, hi));
}

__device__ inline half2_t dup_lo16(unsigned int s) {    // (s&0xFFFF) in both halves
    return __builtin_bit_cast(half2_t, __builtin_amdgcn_perm(0u, s, 0x01000100u));
}

__device__ inline half2_t h2_shfl_xor(half2_t v, int off) {
    return __builtin_bit_cast(half2_t, __shfl_xor(__builtin_bit_cast(unsigned int, v), off));
}

// ---- init global fill counters (cacheline-padded: stride 16 ints) ----
__global__ void init_fill_kernel(int* __restrict__ gfill_r, int* __restrict__ gfill_c,
                                 int NB, int cap) {
    int k = blockIdx.x * blockDim.x + threadIdx.x;
    if (k < NB) {
        gfill_r[k * 16] = k * cap;
        gfill_c[k * 16] = k * cap;
    }
}

// ---- fused binning: per-wave count, block reserve, REGISTER-CACHED place ----
__global__ __launch_bounds__(TPB_BIN)
void binning_kernel(const int* __restrict__ erow, const int* __restrict__ ecol,
                    const float* __restrict__ evals,
                    int* __restrict__ gfill_r, int* __restrict__ gfill_c,
                    ull* __restrict__ br, unsigned int* __restrict__ bc,
                    int E, int NB, int chunk) {
    __shared__ int hr[NWV][MAXNB];
    __shared__ int hc[NWV][MAXNB];
    __shared__ int fr[MAXNB];     // block-level fill cursors (row key)
    __shared__ int fc[MAXNB];     // block-level fill cursors (col key)
    int t = threadIdx.x;
    int wv = t >> 6;
    for (int k = t; k < NWV * MAXNB; k += TPB_BIN) { (&hr[0][0])[k] = 0; (&hc[0][0])[k] = 0; }
    __syncthreads();
    int lo = blockIdx.x * chunk;             // chunk multiple of 4 -> lo 16B-aligned
    int hi = min(E, lo + chunk);
    int nq = (hi - lo) >> 2;
    int rem = (hi - lo) & 3;
    // phase 1: per-wave count; cache edge data in registers (chunk <= 8*TPB -> <=2 iters)
    int p0 = t, p1 = t + TPB_BIN;
    bool h0 = p0 < nq, h1 = p1 < nq;
    int4 r40, c40, r41, c41;
    float4 v40, v41;
    if (h0) {
        int i = lo + 4 * p0;
        r40 = *(const int4*)(erow + i);
        c40 = *(const int4*)(ecol + i);
        v40 = *(const float4*)(evals + i);
        atomicAdd(&hr[wv][r40.x >> 8], 1);
        atomicAdd(&hr[wv][r40.y >> 8], 1);
        atomicAdd(&hr[wv][r40.z >> 8], 1);
        atomicAdd(&hr[wv][r40.w >> 8], 1);
        atomicAdd(&hc[wv][c40.x >> 8], 1);
        atomicAdd(&hc[wv][c40.y >> 8], 1);
        atomicAdd(&hc[wv][c40.z >> 8], 1);
        atomicAdd(&hc[wv][c40.w >> 8], 1);
    }
    if (h1) {
        int i = lo + 4 * p1;
        r41 = *(const int4*)(erow + i);
        c41 = *(const int4*)(ecol + i);
        v41 = *(const float4*)(evals + i);
        atomicAdd(&hr[wv][r41.x >> 8], 1);
        atomicAdd(&hr[wv][r41.y >> 8], 1);
        atomicAdd(&hr[wv][r41.z >> 8], 1);
        atomicAdd(&hr[wv][r41.w >> 8], 1);
        atomicAdd(&hc[wv][c41.x >> 8], 1);
        atomicAdd(&hc[wv][c41.y >> 8], 1);
        atomicAdd(&hc[wv][c41.z >> 8], 1);
        atomicAdd(&hc[wv][c41.w >> 8], 1);
    }
    if (t == 0) {
        for (int i = hi - rem; i < hi; i++) {
            atomicAdd(&hr[0][erow[i] >> 8], 1);
            atomicAdd(&hc[0][ecol[i] >> 8], 1);
        }
    }
    __syncthreads();
    // phase 2: ONE reservation per (block,bucket) -> long contiguous output runs
    if (t < NB) {
        int sr = 0, sc = 0;
        #pragma unroll
        for (int w2 = 0; w2 < NWV; w2++) { sr += hr[w2][t]; sc += hc[w2][t]; }
        fr[t] = atomicAdd(&gfill_r[t * 16], sr);
        fc[t] = atomicAdd(&gfill_c[t * 16], sc);
    }
    __syncthreads();
    // phase 3: place from registers (no global re-read)
    if (h0) {
        int pos0 = atomicAdd(&fr[r40.x >> 8], 1);
        int pos1 = atomicAdd(&fr[r40.y >> 8], 1);
        int pos2 = atomicAdd(&fr[r40.z >> 8], 1);
        int pos3 = atomicAdd(&fr[r40.w >> 8], 1);
        br[pos0] = ((ull)__float_as_uint(v40.x) << 32) | ((ull)(r40.x & 255) << LRSHIFT) | (unsigned)c40.x;
        br[pos1] = ((ull)__float_as_uint(v40.y) << 32) | ((ull)(r40.y & 255) << LRSHIFT) | (unsigned)c40.y;
        br[pos2] = ((ull)__float_as_uint(v40.z) << 32) | ((ull)(r40.z & 255) << LRSHIFT) | (unsigned)c40.z;
        br[pos3] = ((ull)__float_as_uint(v40.w) << 32) | ((ull)(r40.w & 255) << LRSHIFT) | (unsigned)c40.w;
        int q0 = atomicAdd(&fc[c40.x >> 8], 1);
        int q1 = atomicAdd(&fc[c40.y >> 8], 1);
        int q2 = atomicAdd(&fc[c40.z >> 8], 1);
        int q3 = atomicAdd(&fc[c40.w >> 8], 1);
        bc[q0] = bf16_hi(v40.x) | (unsigned)(c40.x & 255);
        bc[q1] = bf16_hi(v40.y) | (unsigned)(c40.y & 255);
        bc[q2] = bf16_hi(v40.z) | (unsigned)(c40.z & 255);
        bc[q3] = bf16_hi(v40.w) | (unsigned)(c40.w & 255);
    }
    if (h1) {
        int pos0 = atomicAdd(&fr[r41.x >> 8], 1);
        int pos1 = atomicAdd(&fr[r41.y >> 8], 1);
        int pos2 = atomicAdd(&fr[r41.z >> 8], 1);
        int pos3 = atomicAdd(&fr[r41.w >> 8], 1);
        br[pos0] = ((ull)__float_as_uint(v41.x) << 32) | ((ull)(r41.x & 255) << LRSHIFT) | (unsigned)c41.x;
        br[pos1] = ((ull)__float_as_uint(v41.y) << 32) | ((ull)(r41.y & 255) << LRSHIFT) | (unsigned)c41.y;
        br[pos2] = ((ull)__float_as_uint(v41.z) << 32) | ((ull)(r41.z & 255) << LRSHIFT) | (unsigned)c41.z;
        br[pos3] = ((ull)__float_as_uint(v41.w) << 32) | ((ull)(r41.w & 255) << LRSHIFT) | (unsigned)c41.w;
        int q0 = atomicAdd(&fc[c41.x >> 8], 1);
        int q1 = atomicAdd(&fc[c41.y >> 8], 1);
        int q2 = atomicAdd(&fc[c41.z >> 8], 1);
        int q3 = atomicAdd(&fc[c41.w >> 8], 1);
        bc[q0] = bf16_hi(v41.x) | (unsigned)(c41.x & 255);
        bc[q1] = bf16_hi(v41.y) | (unsigned)(c41.y & 255);
        bc[q2] = bf16_hi(v41.z) | (unsigned)(c41.z & 255);
        bc[q3] = bf16_hi(v41.w) | (unsigned)(c41.w & 255);
    }
    if (t == 0) {
        for (int i = hi - rem; i < hi; i++) {
            int r = erow[i], c = ecol[i];
            float v = evals[i];
            int pos = atomicAdd(&fr[r >> 8], 1);
            br[pos] = ((ull)__float_as_uint(v) << 32) | ((ull)(r & 255) << LRSHIFT) | (unsigned)c;
            int pos2 = atomicAdd(&fc[c >> 8], 1);
            bc[pos2] = bf16_hi(v) | (unsigned)(c & 255);
        }
    }
}

// ---- fused count+scan+place: one block per bucket; inv_c deferred to features ----
// cw weight = v * inv_r[row] only.  inv_c is applied to the FEATURES (cvt pre-scales
// layer 0; spmm epilogue scales its output row) and cancels in the loss's L2-normalize.
// This makes placement bucket-local: no cross-bucket scan, no sub* round-trips.
__global__ __launch_bounds__(BUCKET)
void fused_cp_kernel(const ull* __restrict__ br, const unsigned int* __restrict__ bc,
                     const int* __restrict__ gfill_r, const int* __restrict__ gfill_c,
                     int2* __restrict__ rse, float* __restrict__ inv_c,
                     unsigned int* __restrict__ cw, int N, int cap) {
    __shared__ int   cnt[BUCKET];     // counts, then reused as placement cursors
    __shared__ float ds[BUCKET];      // row degree sums
    __shared__ float dsc[BUCKET];     // col degree sums
    __shared__ int   sc[BUCKET];      // scan workspace
    __shared__ float invr[BUCKET];
    int b = blockIdx.x, t = threadIdx.x;
    cnt[t] = 0; ds[t] = 0.0f; dsc[t] = 0.0f;
    __syncthreads();
    int s = b * cap;
    int e = gfill_r[b * 16];
    int m = s + ((e - s) & ~3);
    for (int i = s + 4 * t; i < m; i += 4 * BUCKET) {
        ull p0 = br[i];
        ull p1 = br[i + 1];
        ull p2 = br[i + 2];
        ull p3 = br[i + 3];
        int lr0 = (int)((p0 >> LRSHIFT) & LRMASK);
        int lr1 = (int)((p1 >> LRSHIFT) & LRMASK);
        int lr2 = (int)((p2 >> LRSHIFT) & LRMASK);
        int lr3 = (int)((p3 >> LRSHIFT) & LRMASK);
        atomicAdd(&cnt[lr0], 1);
        atomicAdd(&cnt[lr1], 1);
        atomicAdd(&cnt[lr2], 1);
        atomicAdd(&cnt[lr3], 1);
        atomicAdd(&ds[lr0], __uint_as_float((unsigned)(p0 >> 32)));
        atomicAdd(&ds[lr1], __uint_as_float((unsigned)(p1 >> 32)));
        atomicAdd(&ds[lr2], __uint_as_float((unsigned)(p2 >> 32)));
        atomicAdd(&ds[lr3], __uint_as_float((unsigned)(p3 >> 32)));
    }
    if (t == 0) {
        for (int i = m; i < e; i++) {
            ull p = br[i];
            int lr = (int)((p >> LRSHIFT) & LRMASK);
            atomicAdd(&cnt[lr], 1);
            atomicAdd(&ds[lr], __uint_as_float((unsigned)(p >> 32)));
        }
    }
    int e2 = gfill_c[b * 16];
    int m2 = s + ((e2 - s) & ~3);
    for (int i = s + 4 * t; i < m2; i += 4 * BUCKET) {
        uint4 p = *(const uint4*)(bc + i);
        atomicAdd(&dsc[p.x & 0xFFu], __uint_as_float(p.x & 0xffff0000u));
        atomicAdd(&dsc[p.y & 0xFFu], __uint_as_float(p.y & 0xffff0000u));
        atomicAdd(&dsc[p.z & 0xFFu], __uint_as_float(p.z & 0xffff0000u));
        atomicAdd(&dsc[p.w & 0xFFu], __uint_as_float(p.w & 0xffff0000u));
    }
    if (t == 0) {
        for (int i = m2; i < e2; i++) {
            unsigned int p = bc[i];
            atomicAdd(&dsc[p & 0xFFu], __uint_as_float(p & 0xffff0000u));
        }
    }
    __syncthreads();
    // scan of mod-4-rounded counts (row starts 16B-aligned for uint4 cw quads)
    int c0 = cnt[t];
    int sum4 = (c0 + 3) & ~3;
    sc[t] = sum4;
    __syncthreads();
    for (int off = 1; off < BUCKET; off <<= 1) {
        int v = (t >= off) ? sc[t - off] : 0;
        __syncthreads();
        sc[t] += v;
        __syncthreads();
    }
    int st = s + sc[t] - sum4;
    int node = b * BUCKET + t;
    if (node < N) {
        int2 se;
        se.x = st;
        se.y = st + c0;
        rse[node] = se;
    }
    inv_c[node] = 1.0f / (sqrtf(dsc[t]) + 1e-8f);   // padded nodes never referenced
    invr[t] = 1.0f / (sqrtf(ds[t]) + 1e-8f);
    cnt[t] = st;                                    // reuse as cursor
    __syncthreads();
    // place pass (br slice is L2-hot from phase A)
    for (int i = s + 4 * t; i < m; i += 4 * BUCKET) {
        ull p0 = br[i];
        ull p1 = br[i + 1];
        ull p2 = br[i + 2];
        ull p3 = br[i + 3];
        int c0_ = (int)(p0 & CMASK), c1_ = (int)(p1 & CMASK);
        int c2_ = (int)(p2 & CMASK), c3_ = (int)(p3 & CMASK);
        int lr0 = (int)((p0 >> LRSHIFT) & LRMASK);
        int lr1 = (int)((p1 >> LRSHIFT) & LRMASK);
        int lr2 = (int)((p2 >> LRSHIFT) & LRMASK);
        int lr3 = (int)((p3 >> LRSHIFT) & LRMASK);
        float v0 = __uint_as_float((unsigned)(p0 >> 32));
        float v1 = __uint_as_float((unsigned)(p1 >> 32));
        float v2 = __uint_as_float((unsigned)(p2 >> 32));
        float v3 = __uint_as_float((unsigned)(p3 >> 32));
        int pos0 = atomicAdd(&cnt[lr0], 1);
        int pos1 = atomicAdd(&cnt[lr1], 1);
        int pos2 = atomicAdd(&cnt[lr2], 1);
        int pos3 = atomicAdd(&cnt[lr3], 1);
        float w0 = v0 * invr[lr0];
        float w1 = v1 * invr[lr1];
        float w2 = v2 * invr[lr2];
        float w3 = v3 * invr[lr3];
        cw[pos0] = ((unsigned)c0_ << 15) | ((pk_f16x2(w0, w0) & 0xFFFFu) >> 1);
        cw[pos1] = ((unsigned)c1_ << 15) | ((pk_f16x2(w1, w1) & 0xFFFFu) >> 1);
        cw[pos2] = ((unsigned)c2_ << 15) | ((pk_f16x2(w2, w2) & 0xFFFFu) >> 1);
        cw[pos3] = ((unsigned)c3_ << 15) | ((pk_f16x2(w3, w3) & 0xFFFFu) >> 1);
    }
    if (t == 0) {
        for (int i = m; i < e; i++) {
            ull p = br[i];
            int c = (int)(p & CMASK);
            int lr = (int)((p >> LRSHIFT) & LRMASK);
            float v = __uint_as_float((unsigned)(p >> 32));
            int pos = atomicAdd(&cnt[lr], 1);
            float wv = v * invr[lr];
            cw[pos] = ((unsigned)c << 15) | ((pk_f16x2(wv, wv) & 0xFFFFu) >> 1);
        }
    }
}

// ---- cvt: fb0 = f16(inv_c * nf); 4 floats/thread ----
__global__ void cvt_kernel(const float* __restrict__ src, const float* __restrict__ inv_c,
                           unsigned int* __restrict__ dst, long n4) {
    long i = (long)blockIdx.x * blockDim.x + threadIdx.x;
    if (i < n4) {
        float ic = inv_c[i >> 4];           // 16 threads per 64-float row
        float4 v = ((const float4*)src)[i];
        uint2 o;
        o.x = pk_f16x2(v.x * ic, v.y * ic);
        o.y = pk_f16x2(v.z * ic, v.w * ic);
        ((uint2*)dst)[i] = o;
    }
}

// ---- SpMM: wave per row, 32 edges/iter via uint4 cw quads, batched gathers ----
// fin carries inv_c scale; epilogue multiplies the output row by inv_c[wid] so the
// next layer's gather is correctly scaled. Row-uniform scale cancels in loss norm.
__global__ __launch_bounds__(256)
void spmm_f16_kernel(const int2* __restrict__ rse,
                     const unsigned int* __restrict__ cw,
                     const float* __restrict__ inv_c,
                     const unsigned short* __restrict__ fin,
                     unsigned short* __restrict__ fout, int N) {
    int wid = blockIdx.x * (blockDim.x >> 6) + (threadIdx.x >> 6);   // row
    if (wid >= N) return;
    int lane = threadIdx.x & 63;
    int g = lane >> 3;          // edge-quad slot 0..7 (32 edges per iteration)
    int h = lane & 7;           // feature chunk (8 f16 = 16 B)
    int2 se = rse[wid];
    float ic = inv_c[wid];
    int s = se.x, e = se.y;     // s multiple of 4 -> uint4-aligned cw quads
    half2_t a2[8];
    #pragma unroll
    for (int k = 0; k < 8; k++) a2[k] = (half2_t)0;

    for (int base = s; base < e; base += 32) {
        int j = base + 4 * g;
        if (j < e) {
            uint4 pw = *(const uint4*)(cw + j);
            int c0 = (int)(pw.x >> 15);
            int c1 = (j + 1 < e) ? (int)(pw.y >> 15) : c0;
            int c2 = (j + 2 < e) ? (int)(pw.z >> 15) : c0;
            int c3 = (j + 3 < e) ? (int)(pw.w >> 15) : c0;
            uint4 q0 = ((const uint4*)(fin + ((long)c0 << 6)))[h];
            uint4 q1 = ((const uint4*)(fin + ((long)c1 << 6)))[h];
            uint4 q2 = ((const uint4*)(fin + ((long)c2 << 6)))[h];
            uint4 q3 = ((const uint4*)(fin + ((long)c3 << 6)))[h];
            half2_t w0 = dup_lo16(pw.x << 1);
            half2_t w1 = (j + 1 < e) ? dup_lo16(pw.y << 1) : (half2_t)0;
            half2_t w2 = (j + 2 < e) ? dup_lo16(pw.z << 1) : (half2_t)0;
            half2_t w3 = (j + 3 < e) ? dup_lo16(pw.w << 1) : (half2_t)0;
            a2[0] += w0 * __builtin_bit_cast(half2_t, q0.x);
            a2[1] += w0 * __builtin_bit_cast(half2_t, q0.y);
            a2[2] += w0 * __builtin_bit_cast(half2_t, q0.z);
            a2[3] += w0 * __builtin_bit_cast(half2_t, q0.w);
            a2[4] += w1 * __builtin_bit_cast(half2_t, q1.x);
            a2[5] += w1 * __builtin_bit_cast(half2_t, q1.y);
            a2[6] += w1 * __builtin_bit_cast(half2_t, q1.z);
            a2[7] += w1 * __builtin_bit_cast(half2_t, q1.w);
            a2[0] += w2 * __builtin_bit_cast(half2_t, q2.x);
            a2[1] += w2 * __builtin_bit_cast(half2_t, q2.y);
            a2[2] += w2 * __builtin_bit_cast(half2_t, q2.z);
            a2[3] += w2 * __builtin_bit_cast(half2_t, q2.w);
            a2[4] += w3 * __builtin_bit_cast(half2_t, q3.x);
            a2[5] += w3 * __builtin_bit_cast(half2_t, q3.y);
            a2[6] += w3 * __builtin_bit_cast(half2_t, q3.z);
            a2[7] += w3 * __builtin_bit_cast(half2_t, q3.w);
        }
    }

    // reduce slot partials across lane groups; lanes g==0 scale by inv_c and write
    #pragma unroll
    for (int k = 0; k < 4; k++) a2[k] += a2[k + 4];
    #pragma unroll
    for (int k = 0; k < 4; k++) {
        a2[k] += h2_shfl_xor(a2[k], 8);
        a2[k] += h2_shfl_xor(a2[k], 16);
        a2[k] += h2_shfl_xor(a2[k], 32);
    }
    if (g == 0) {
        half2_t ich = __builtin_bit_cast(half2_t, pk_f16x2(ic, ic));
        uint4 o;
        o.x = __builtin_bit_cast(unsigned int, a2[0] * ich);
        o.y = __builtin_bit_cast(unsigned int, a2[1] * ich);
        o.z = __builtin_bit_cast(unsigned int, a2[2] * ich);
        o.w = __builtin_bit_cast(unsigned int, a2[3] * ich);
        ((uint4*)(fout + ((long)wid << 6)))[h] = o;
    }
}

// ---- loss: reconstruct rep rows on the fly (f32 norms, layer-0 from f32 nf) ----
// stored_l = inv_c * x_l (row-uniform positive scale) -> x_l/||x_l|| == stored/||stored||
__device__ inline float rep_at(const float* __restrict__ nf,
                               const unsigned short* __restrict__ f1,
                               const unsigned short* __restrict__ f2,
                               const unsigned short* __restrict__ f3,
                               int id, int lane) {
    long off = (long)id * DDIM + lane;
    float r  = nf[off];
    float v1 = (float)__builtin_bit_cast(_Float16, f1[off]);
    float v2 = (float)__builtin_bit_cast(_Float16, f2[off]);
    float v3 = (float)__builtin_bit_cast(_Float16, f3[off]);
    float s1 = v1 * v1, s2 = v2 * v2, s3 = v3 * v3;
    #pragma unroll
    for (int o = 1; o < 64; o <<= 1) {
        s1 += __shfl_xor(s1, o);
        s2 += __shfl_xor(s2, o);
        s3 += __shfl_xor(s3, o);
    }
    r += v1 / fmaxf(sqrtf(s1), 1e-12f);
    r += v2 / fmaxf(sqrtf(s2), 1e-12f);
    r += v3 / fmaxf(sqrtf(s3), 1e-12f);
    return r;
}

__global__ void loss_terms_kernel(const float* __restrict__ nf,
                                  const unsigned short* __restrict__ f1,
                                  const unsigned short* __restrict__ f2,
                                  const unsigned short* __restrict__ f3,
                                  const int* __restrict__ a_id, const int* __restrict__ p_id,
                                  const int* __restrict__ n_id,
                                  float* __restrict__ terms, int B) {
    long gid = (long)blockIdx.x * blockDim.x + threadIdx.x;
    int b = (int)(gid >> 6);
    int lane = threadIdx.x & 63;
    if (b < B) {
        float ra = rep_at(nf, f1, f2, f3, a_id[b], lane);
        float rp = rep_at(nf, f1, f2, f3, p_id[b], lane);
        float rn = rep_at(nf, f1, f2, f3, n_id[b], lane);
        float dp = ra * rp, dn = ra * rn;
        #pragma unroll
        for (int off = 1; off < 64; off <<= 1) { dp += __shfl_xor(dp, off); dn += __shfl_xor(dn, off); }
        if (lane == 0) {
            float x = (dp - dn) * 0.0625f;   // node_rep = rep/4 -> preds scale 1/16
            terms[b] = fmaxf(-x, 0.0f) + log1pf(expf(-fabsf(x)));
        }
    }
}

__global__ void reduce_kernel(const float* __restrict__ terms, float* __restrict__ out, int B) {
    __shared__ float sm[256];
    float s = 0.0f;
    for (int i = threadIdx.x; i < B; i += 256) s += terms[i];
    sm[threadIdx.x] = s;
    __syncthreads();
    for (int stride = 128; stride > 0; stride >>= 1) {
        if (threadIdx.x < stride) sm[threadIdx.x] += sm[threadIdx.x + stride];
        __syncthreads();
    }
    if (threadIdx.x == 0) out[0] = sm[0] / (float)B;
}

extern "C" void kernel_launch(void* const* d_in, const int* in_sizes, int n_in,
                              void* d_out, int out_size, void* d_ws, size_t ws_size,
                              hipStream_t stream) {
    const float* nf    = (const float*)d_in[0];
    const int*   erow  = (const int*)d_in[1];
    const int*   ecol  = (const int*)d_in[2];
    const float* evals = (const float*)d_in[3];
    const int*   a_id  = (const int*)d_in[4];
    const int*   p_id  = (const int*)d_in[5];
    const int*   n_id  = (const int*)d_in[6];

    int N = in_sizes[0] / DDIM;
    int E = in_sizes[1];
    int B = in_sizes[4];
    int NB = (N + BUCKET - 1) / BUCKET;
    int chunk = (((E + NBLK - 1) / NBLK) + 3) & ~3;   // multiple of 4 -> aligned quad loads
    int Npad = NB * BUCKET;

    // bucket capacity: mean + 12.5% (binomial tail, sigma~90 -> >20 sigma) + 2048
    // (mod-4 rounding pad <=768 + guard)
    long capl = ((long)E * BUCKET) / N;
    int cap = (int)(capl + capl / 8 + 2048);
    cap = (cap + 63) & ~63;

    size_t regionA = (size_t)cap * NB * 8;            // br (8 B), later fb0+fb1
    size_t regionB = (size_t)cap * NB * 4;            // bc (4 B), later cw (4 B)
    size_t featB16 = (size_t)N * DDIM * 2;
    if (regionA < 2 * featB16) regionA = 2 * featB16;

    char* w = (char*)d_ws;
    ull*  br     = (ull*)w;
    char* regAp  = w;                 w += regionA;
    unsigned int* bc = (unsigned int*)w;
    unsigned int* cw = (unsigned int*)w;  w += regionB + 256;  // +256: spmm quad tail overread pad
    unsigned short* fb2 = (unsigned short*)w;  w += featB16;   // layer-2 output
    float* inv_c = (float*)w;         w += (size_t)Npad * 4;
    int2* rse    = (int2*)w;          w += (size_t)N * 8;
    int* gfill_r = (int*)w;           w += (size_t)NB * 16 * 4;
    int* gfill_c = (int*)w;           w += (size_t)NB * 16 * 4;
    float* terms = (float*)w;         w += (size_t)B * 4;

    unsigned short* fb0 = (unsigned short*)regAp;             // aliases br (dead after fused_cp)
    unsigned short* fb1 = (unsigned short*)(regAp + featB16);

    init_fill_kernel<<<(unsigned)((NB + 127) / 128), 128, 0, stream>>>(gfill_r, gfill_c, NB, cap);
    binning_kernel<<<NBLK, TPB_BIN, 0, stream>>>(erow, ecol, evals, gfill_r, gfill_c,
                                                 br, bc, E, NB, chunk);
    fused_cp_kernel<<<NB, BUCKET, 0, stream>>>(br, bc, gfill_r, gfill_c,
                                               rse, inv_c, cw, N, cap);

    long n4 = (long)N * DDIM / 4;
    cvt_kernel<<<(unsigned)((n4 + 255) / 256), 256, 0, stream>>>(nf, inv_c, (unsigned int*)fb0, n4);

    unsigned spmmGrid = (unsigned)((N + 3) / 4);   // 4 waves (rows) per 256-thread block
    // layers: fb0 -> fb1 -> fb2 -> fb0 (fb0 slot reused; loss reads f32 nf for layer 0)
    spmm_f16_kernel<<<spmmGrid, 256, 0, stream>>>(rse, cw, inv_c, fb0, fb1, N);
    spmm_f16_kernel<<<spmmGrid, 256, 0, stream>>>(rse, cw, inv_c, fb1, fb2, N);
    spmm_f16_kernel<<<spmmGrid, 256, 0, stream>>>(rse, cw, inv_c, fb2, fb0, N);

    loss_terms_kernel<<<(unsigned)(((long)B * 64 + 255) / 256), 256, 0, stream>>>(
        nf, fb1, fb2, fb0, a_id, p_id, n_id, terms, B);
    reduce_kernel<<<1, 256, 0, stream>>>(terms, (float*)d_out, B);
}